// Round 1
// 320.309 us; speedup vs baseline: 1.0108x; 1.0108x over previous
//
#include <hip/hip_runtime.h>

// Problem constants: B=8, N=1024, C=64, O=64, K+1=4
#define EPS_Q 1e-12f

// Native clang vector for __builtin_nontemporal_load (HIP_vector_type is
// rejected by the builtin's type checker).
typedef float nfloat4 __attribute__((ext_vector_type(4)));

__device__ __forceinline__ float wave_reduce_sum(float v) {
#pragma unroll
    for (int m = 32; m > 0; m >>= 1) v += __shfl_xor(v, m, 64);
    return v;
}

// ---------------------------------------------------------------------------
// Kernel A: per-node attention scores. One wave per row (b*N+n), lane = c.
// Outputs SoA: sRi/sIi (row term), sRj/sIj (col term) so that k_rowreduce's
// register prelude loads are float4-coalesced.
// ---------------------------------------------------------------------------
__global__ __launch_bounds__(256)
void k_scores(const float* __restrict__ Xr, const float* __restrict__ Xi,
              const float* __restrict__ awr, const float* __restrict__ awi,
              float* __restrict__ sRi, float* __restrict__ sIi,
              float* __restrict__ sRj, float* __restrict__ sIj) {
    const int lane = threadIdx.x & 63;
    const int row  = (blockIdx.x << 2) + (threadIdx.x >> 6);  // b*N + n
    const float xr = Xr[row * 64 + lane];
    const float xi = Xi[row * 64 + lane];
    const float wri = awr[lane], wrj = awr[64 + lane];
    const float wii = awi[lane], wij = awi[64 + lane];
    float v0 = xr * wri - xi * wii;   // sR_i partial
    float v1 = xr * wii + xi * wri;   // sI_i partial
    float v2 = xr * wrj - xi * wij;   // sR_j partial
    float v3 = xr * wij + xi * wrj;   // sI_j partial
#pragma unroll
    for (int m = 32; m > 0; m >>= 1) {
        v0 += __shfl_xor(v0, m, 64);
        v1 += __shfl_xor(v1, m, 64);
        v2 += __shfl_xor(v2, m, 64);
        v3 += __shfl_xor(v3, m, 64);
    }
    if (lane == 0) {
        sRi[row] = v0;
        sIi[row] = v1;
        sRj[row] = v2;
        sIj[row] = v3;
    }
}

// ---------------------------------------------------------------------------
// Kernel B: column softmax stats over axis i for each (b, j). One wave per
// (b, j). Writes cmax = colmax, cinv = 1/sum(exp(mag-colmax)) (SoA).
// ---------------------------------------------------------------------------
__global__ __launch_bounds__(256)
void k_softmax(const float* __restrict__ sRi, const float* __restrict__ sIi,
               const float* __restrict__ sRj, const float* __restrict__ sIj,
               float* __restrict__ cmax, float* __restrict__ cinv,
               const float* __restrict__ abr, const float* __restrict__ abi,
               const float* __restrict__ par_, const float* __restrict__ pai_) {
    const int lane = threadIdx.x & 63;
    const int row  = (blockIdx.x << 2) + (threadIdx.x >> 6);  // b*N + j
    const int b    = row >> 10;
    const float br = abr[0], bi = abi[0], par = par_[0], pai = pai_[0];
    const float sRjv = sRj[row], sIjv = sIj[row];
    const float* pR = sRi + (b << 10);
    const float* pI = sIi + (b << 10);
    float mags[16];
    float mx = -3.4e38f;
#pragma unroll
    for (int t = 0; t < 16; ++t) {
        const int i = (t << 6) + lane;
        float sr = pR[i] + sRjv + br;
        float si = pI[i] + sIjv + bi;
        float pr = sr >= 0.f ? sr : par * sr;
        float pi = si >= 0.f ? si : pai * si;
        float mg = sqrtf(pr * pr + pi * pi);
        mags[t] = mg;
        mx = fmaxf(mx, mg);
    }
#pragma unroll
    for (int m = 32; m > 0; m >>= 1) mx = fmaxf(mx, __shfl_xor(mx, m, 64));
    float s = 0.f;
#pragma unroll
    for (int t = 0; t < 16; ++t) s += __expf(mags[t] - mx);
    s = wave_reduce_sum(s);
    if (lane == 0) {
        cmax[row] = mx;
        cinv[row] = 1.f / s;
    }
}

// ---------------------------------------------------------------------------
// Helper: attention coefficient for one (i,j) from SoA stats.
// ---------------------------------------------------------------------------
__device__ __forceinline__ void attn_coef(float srj, float sij, float mx, float is,
                                          float sri, float sii,
                                          float br, float bi, float par, float pai,
                                          float& ar, float& ai) {
    float sr = sri + srj + br;
    float si = sii + sij + bi;
    float pr = sr >= 0.f ? sr : par * sr;
    float pi = si >= 0.f ? si : pai * si;
    float mg = sqrtf(pr * pr + pi * pi);
    float sc = __expf(mg - mx) * is / (mg + EPS_Q);
    ar = sc * pr;
    ai = sc * pi;
}

// ---------------------------------------------------------------------------
// Kernel C: the 268 MB streaming kernel, R8: barrier-free, LDS-free.
// One wave per (b,i) row; the wave owns all 4 m-slices (32 KB of L).
//  - Prelude: each lane computes its 16 ar/ai coefficients IN REGISTERS from
//    the SoA stats (16 coalesced dwordx4 loads from L2-hot 4 KB arrays).
//    Total coefficient compute is unchanged vs the LDS version — each (b,i,j)
//    is still computed exactly once — only its distribution changed.
//  - Stream: 4 m-slices of NT dwordx4 loads with nothing between bursts but
//    FMAs. No __syncthreads, no LDS, no inter-wave coupling: waves spend
//    ~all their lifetime with 8-16 loads in flight (vs ~30% duty cycle of
//    the phase-split LDS version; R7's Little's-law wall).
// ~125 VGPR -> >=12 waves/CU, each with up to 16 KB in flight >> the ~9 KB/CU
// needed to saturate 6.3 TB/s at ~900 cy HBM latency.
// ---------------------------------------------------------------------------
__global__ __launch_bounds__(256)
void k_rowreduce(const float* __restrict__ Lr, const float* __restrict__ Li,
                 const float* __restrict__ sRi, const float* __restrict__ sIi,
                 const float* __restrict__ sRj, const float* __restrict__ sIj,
                 const float* __restrict__ cmax, const float* __restrict__ cinv,
                 const float* __restrict__ abr, const float* __restrict__ abi,
                 const float* __restrict__ par_, const float* __restrict__ pai_,
                 float* __restrict__ rowR, float* __restrict__ rowI) {
    const int lane = threadIdx.x & 63;
    const int wid  = (blockIdx.x << 2) + (threadIdx.x >> 6);  // b*N + i
    const int b    = wid >> 10;
    const int i    = wid & 1023;
    const float br = abr[0], bi = abi[0], par = par_[0], pai = pai_[0];
    const float sri = sRi[wid], sii = sIi[wid];

    const float4* SRJ = (const float4*)(sRj + (b << 10));
    const float4* SIJ = (const float4*)(sIj + (b << 10));
    const float4* CMX = (const float4*)(cmax + (b << 10));
    const float4* CIV = (const float4*)(cinv + (b << 10));

    // Prelude: 16 ar/ai pairs per lane, j = 4*(t*64+lane)+e.
    float arv[16], aiv[16];
#pragma unroll
    for (int t = 0; t < 4; ++t) {
        const int j4 = (t << 6) + lane;
        const float4 vr = SRJ[j4];
        const float4 vi = SIJ[j4];
        const float4 vm = CMX[j4];
        const float4 vs = CIV[j4];
        attn_coef(vr.x, vi.x, vm.x, vs.x, sri, sii, br, bi, par, pai,
                  arv[(t << 2) + 0], aiv[(t << 2) + 0]);
        attn_coef(vr.y, vi.y, vm.y, vs.y, sri, sii, br, bi, par, pai,
                  arv[(t << 2) + 1], aiv[(t << 2) + 1]);
        attn_coef(vr.z, vi.z, vm.z, vs.z, sri, sii, br, bi, par, pai,
                  arv[(t << 2) + 2], aiv[(t << 2) + 2]);
        attn_coef(vr.w, vi.w, vm.w, vs.w, sri, sii, br, bi, par, pai,
                  arv[(t << 2) + 3], aiv[(t << 2) + 3]);
    }

    // Stream: L[b,m,i,:] for m=0..3. float4-index stride per m = 1<<18.
    const size_t rb = ((size_t)b << 22) + ((size_t)i << 10);
    const nfloat4* LR = (const nfloat4*)(Lr + rb);
    const nfloat4* LI = (const nfloat4*)(Li + rb);

    float accR[4] = {0.f, 0.f, 0.f, 0.f};
    float accI[4] = {0.f, 0.f, 0.f, 0.f};
#pragma unroll
    for (int m = 0; m < 4; ++m) {
        nfloat4 r[4], q[4];
#pragma unroll
        for (int t = 0; t < 4; ++t) {
            r[t] = __builtin_nontemporal_load(&LR[(m << 18) + (t << 6) + lane]);
            q[t] = __builtin_nontemporal_load(&LI[(m << 18) + (t << 6) + lane]);
        }
#pragma unroll
        for (int t = 0; t < 4; ++t) {
            accR[m] += r[t].x * arv[(t << 2) + 0] - q[t].x * aiv[(t << 2) + 0];
            accI[m] += r[t].x * aiv[(t << 2) + 0] + q[t].x * arv[(t << 2) + 0];
            accR[m] += r[t].y * arv[(t << 2) + 1] - q[t].y * aiv[(t << 2) + 1];
            accI[m] += r[t].y * aiv[(t << 2) + 1] + q[t].y * arv[(t << 2) + 1];
            accR[m] += r[t].z * arv[(t << 2) + 2] - q[t].z * aiv[(t << 2) + 2];
            accI[m] += r[t].z * aiv[(t << 2) + 2] + q[t].z * arv[(t << 2) + 2];
            accR[m] += r[t].w * arv[(t << 2) + 3] - q[t].w * aiv[(t << 2) + 3];
            accI[m] += r[t].w * aiv[(t << 2) + 3] + q[t].w * arv[(t << 2) + 3];
        }
    }

#pragma unroll
    for (int m = 0; m < 4; ++m) {
        float aR = accR[m], aI = accI[m];
#pragma unroll
        for (int s = 32; s > 0; s >>= 1) {
            aR += __shfl_xor(aR, s, 64);
            aI += __shfl_xor(aI, s, 64);
        }
        if (lane == 0) {
            rowR[((b << 2) + m) * 1024 + i] = aR;
            rowI[((b << 2) + m) * 1024 + i] = aI;
        }
    }
}

// ---------------------------------------------------------------------------
// Kernel D: out[b,j,o] recombination; one wave handles 4 rows (register
// blocked); X rows staged in LDS. (Unchanged — ~8 us, L2-hot weights.)
// ---------------------------------------------------------------------------
__global__ __launch_bounds__(256)
void k_output(const float* __restrict__ Xr, const float* __restrict__ Xi,
              const float* __restrict__ wr, const float* __restrict__ wi,
              const float* __restrict__ rowR, const float* __restrict__ rowI,
              float* __restrict__ out) {
    __shared__ float lxr[16][64];
    __shared__ float lxi[16][64];
    const int tid = threadIdx.x;
    const int rb  = blockIdx.x << 4;  // 16 rows per block
    {
        const float4* s0 = (const float4*)(Xr + (size_t)rb * 64);
        const float4* s1 = (const float4*)(Xi + (size_t)rb * 64);
        ((float4*)&lxr[0][0])[tid] = s0[tid];  // 16*64 floats = 256 float4
        ((float4*)&lxi[0][0])[tid] = s1[tid];
    }
    __syncthreads();
    const int wave = tid >> 6, lane = tid & 63;
    const int r0 = wave << 2;  // 4 rows per wave
    float u[4][4], v[4][4];
#pragma unroll
    for (int r = 0; r < 4; ++r)
#pragma unroll
        for (int m = 0; m < 4; ++m) { u[r][m] = 0.f; v[r][m] = 0.f; }
    for (int c = 0; c < 64; ++c) {
        float wrv[4], wiv[4];
#pragma unroll
        for (int m = 0; m < 4; ++m) {
            wrv[m] = wr[((m << 6) + c) * 64 + lane];
            wiv[m] = wi[((m << 6) + c) * 64 + lane];
        }
#pragma unroll
        for (int r = 0; r < 4; ++r) {
            const float xr = lxr[r0 + r][c];
            const float xi = lxi[r0 + r][c];
#pragma unroll
            for (int m = 0; m < 4; ++m) {
                u[r][m] += xr * wrv[m];
                v[r][m] += xi * wiv[m];
            }
        }
    }
#pragma unroll
    for (int r = 0; r < 4; ++r) {
        const int row = rb + r0 + r;  // b*N + j
        const int b = row >> 10, j = row & 1023;
        float re = 0.f, im = 0.f;
#pragma unroll
        for (int m = 0; m < 4; ++m) {
            const float rr = rowR[(b << 12) + (m << 10) + j];
            const float ri = rowI[(b << 12) + (m << 10) + j];
            re += rr * u[r][m] - ri * v[r][m];
            im += ri * u[r][m] + rr * v[r][m];
        }
        out[(size_t)row * 64 + lane] = re;
        out[524288 + (size_t)row * 64 + lane] = im;  // imag block
    }
}

extern "C" void kernel_launch(void* const* d_in, const int* in_sizes, int n_in,
                              void* d_out, int out_size, void* d_ws, size_t ws_size,
                              hipStream_t stream) {
    const float* Xr  = (const float*)d_in[0];
    const float* Xi  = (const float*)d_in[1];
    const float* Lr  = (const float*)d_in[2];
    const float* Li  = (const float*)d_in[3];
    const float* wr  = (const float*)d_in[4];
    const float* wi  = (const float*)d_in[5];
    const float* awr = (const float*)d_in[6];
    const float* awi = (const float*)d_in[7];
    const float* abr = (const float*)d_in[8];
    const float* abi = (const float*)d_in[9];
    const float* par = (const float*)d_in[10];
    const float* pai = (const float*)d_in[11];
    float* out = (float*)d_out;

    // Workspace layout (floats), all 32 KB-aligned blocks:
    // sRi[8192] sIi[8192] sRj[8192] sIj[8192] cmax[8192] cinv[8192]
    // rowR[32768] rowI[32768]   (total 448 KB)
    float* ws   = (float*)d_ws;
    float* sRi  = ws;
    float* sIi  = ws + 8192;
    float* sRj  = ws + 16384;
    float* sIj  = ws + 24576;
    float* cmax = ws + 32768;
    float* cinv = ws + 40960;
    float* rowR = ws + 49152;
    float* rowI = ws + 81920;

    k_scores   <<<dim3(2048), dim3(256), 0, stream>>>(Xr, Xi, awr, awi, sRi, sIi, sRj, sIj);
    k_softmax  <<<dim3(2048), dim3(256), 0, stream>>>(sRi, sIi, sRj, sIj, cmax, cinv,
                                                      abr, abi, par, pai);
    k_rowreduce<<<dim3(2048), dim3(256), 0, stream>>>(Lr, Li, sRi, sIi, sRj, sIj, cmax, cinv,
                                                      abr, abi, par, pai, rowR, rowI);
    k_output   <<<dim3(512),  dim3(256), 0, stream>>>(Xr, Xi, wr, wi, rowR, rowI, out);
}

// Round 2
// 309.549 us; speedup vs baseline: 1.0460x; 1.0348x over previous
//
#include <hip/hip_runtime.h>

// Problem constants: B=8, N=1024, C=64, O=64, K+1=4
#define EPS_Q 1e-12f

// Native clang vector for __builtin_nontemporal_load (HIP_vector_type is
// rejected by the builtin's type checker).
typedef float nfloat4 __attribute__((ext_vector_type(4)));

__device__ __forceinline__ float wave_reduce_sum(float v) {
#pragma unroll
    for (int m = 32; m > 0; m >>= 1) v += __shfl_xor(v, m, 64);
    return v;
}

// ---------------------------------------------------------------------------
// Kernel A: per-node attention scores. One wave per row (b*N+n), lane = c.
// Outputs SoA: sRi/sIi (row term), sRj/sIj (col term) so that the streaming
// kernel's register prelude loads are float4-coalesced.
// ---------------------------------------------------------------------------
__global__ __launch_bounds__(256)
void k_scores(const float* __restrict__ Xr, const float* __restrict__ Xi,
              const float* __restrict__ awr, const float* __restrict__ awi,
              float* __restrict__ sRi, float* __restrict__ sIi,
              float* __restrict__ sRj, float* __restrict__ sIj) {
    const int lane = threadIdx.x & 63;
    const int row  = (blockIdx.x << 2) + (threadIdx.x >> 6);  // b*N + n
    const float xr = Xr[row * 64 + lane];
    const float xi = Xi[row * 64 + lane];
    const float wri = awr[lane], wrj = awr[64 + lane];
    const float wii = awi[lane], wij = awi[64 + lane];
    float v0 = xr * wri - xi * wii;   // sR_i partial
    float v1 = xr * wii + xi * wri;   // sI_i partial
    float v2 = xr * wrj - xi * wij;   // sR_j partial
    float v3 = xr * wij + xi * wrj;   // sI_j partial
#pragma unroll
    for (int m = 32; m > 0; m >>= 1) {
        v0 += __shfl_xor(v0, m, 64);
        v1 += __shfl_xor(v1, m, 64);
        v2 += __shfl_xor(v2, m, 64);
        v3 += __shfl_xor(v3, m, 64);
    }
    if (lane == 0) {
        sRi[row] = v0;
        sIi[row] = v1;
        sRj[row] = v2;
        sIj[row] = v3;
    }
}

// ---------------------------------------------------------------------------
// Kernel B: column softmax stats over axis i for each (b, j). One wave per
// (b, j). Writes cmax = colmax, cinv = 1/sum(exp(mag-colmax)) (SoA).
// ---------------------------------------------------------------------------
__global__ __launch_bounds__(256)
void k_softmax(const float* __restrict__ sRi, const float* __restrict__ sIi,
               const float* __restrict__ sRj, const float* __restrict__ sIj,
               float* __restrict__ cmax, float* __restrict__ cinv,
               const float* __restrict__ abr, const float* __restrict__ abi,
               const float* __restrict__ par_, const float* __restrict__ pai_) {
    const int lane = threadIdx.x & 63;
    const int row  = (blockIdx.x << 2) + (threadIdx.x >> 6);  // b*N + j
    const int b    = row >> 10;
    const float br = abr[0], bi = abi[0], par = par_[0], pai = pai_[0];
    const float sRjv = sRj[row], sIjv = sIj[row];
    const float* pR = sRi + (b << 10);
    const float* pI = sIi + (b << 10);
    float mags[16];
    float mx = -3.4e38f;
#pragma unroll
    for (int t = 0; t < 16; ++t) {
        const int i = (t << 6) + lane;
        float sr = pR[i] + sRjv + br;
        float si = pI[i] + sIjv + bi;
        float pr = sr >= 0.f ? sr : par * sr;
        float pi = si >= 0.f ? si : pai * si;
        float mg = sqrtf(pr * pr + pi * pi);
        mags[t] = mg;
        mx = fmaxf(mx, mg);
    }
#pragma unroll
    for (int m = 32; m > 0; m >>= 1) mx = fmaxf(mx, __shfl_xor(mx, m, 64));
    float s = 0.f;
#pragma unroll
    for (int t = 0; t < 16; ++t) s += __expf(mags[t] - mx);
    s = wave_reduce_sum(s);
    if (lane == 0) {
        cmax[row] = mx;
        cinv[row] = 1.f / s;
    }
}

// ---------------------------------------------------------------------------
// Helper: attention coefficient for one (i,j) from SoA stats.
// ---------------------------------------------------------------------------
__device__ __forceinline__ void attn_coef(float srj, float sij, float mx, float is,
                                          float sri, float sii,
                                          float br, float bi, float par, float pai,
                                          float& ar, float& ai) {
    float sr = sri + srj + br;
    float si = sii + sij + bi;
    float pr = sr >= 0.f ? sr : par * sr;
    float pi = si >= 0.f ? si : pai * si;
    float mg = sqrtf(pr * pr + pi * pi);
    float sc = __expf(mg - mx) * is / (mg + EPS_Q);
    ar = sc * pr;
    ai = sc * pi;
}

#define FMA_BURST(m, R, Q)                                              \
    {                                                                   \
        _Pragma("unroll")                                               \
        for (int t = 0; t < 4; ++t) {                                   \
            accR[m] += R[t].x * arv[(t << 2) + 0] - Q[t].x * aiv[(t << 2) + 0]; \
            accI[m] += R[t].x * aiv[(t << 2) + 0] + Q[t].x * arv[(t << 2) + 0]; \
            accR[m] += R[t].y * arv[(t << 2) + 1] - Q[t].y * aiv[(t << 2) + 1]; \
            accI[m] += R[t].y * aiv[(t << 2) + 1] + Q[t].y * arv[(t << 2) + 1]; \
            accR[m] += R[t].z * arv[(t << 2) + 2] - Q[t].z * aiv[(t << 2) + 2]; \
            accI[m] += R[t].z * aiv[(t << 2) + 2] + Q[t].z * arv[(t << 2) + 2]; \
            accR[m] += R[t].w * arv[(t << 2) + 3] - Q[t].w * aiv[(t << 2) + 3]; \
            accI[m] += R[t].w * aiv[(t << 2) + 3] + Q[t].w * arv[(t << 2) + 3]; \
        }                                                               \
    }

#define LOAD_BURST(m, R, Q)                                             \
    {                                                                   \
        _Pragma("unroll")                                               \
        for (int t = 0; t < 4; ++t) {                                   \
            R[t] = __builtin_nontemporal_load(&LR[((m) << 18) + (t << 6) + lane]); \
            Q[t] = __builtin_nontemporal_load(&LI[((m) << 18) + (t << 6) + lane]); \
        }                                                               \
    }

// ---------------------------------------------------------------------------
// Kernel C (R9): streaming row-reduce FUSED with output recombination.
// One wave per (b,i). Three phases:
//  1. Prelude: 16 ar/ai coefficient pairs per lane, in registers (SoA stats).
//  2. Stream: 4 m-slices of L (32 KB) with an explicit 2-deep m-pipeline
//     (two buffer sets; loads for m+2 issued between FMA bursts) -> there is
//     always >=1 burst (8 dwordx4) in flight per wave until the last burst.
//     Butterfly reduce leaves rowR/rowI[m] in ALL lanes -> no global
//     round-trip, no lane0 stores.
//  3. Output: the block's 4 waves split the recombine GEMM by weight-plane
//     m==wave (each wave reads only its 32 KB wr/wi plane -> total L2 weight
//     traffic stays at 256 MB, same as the old standalone k_output), exchange
//     the 8 KB u/v panels via LDS (one barrier), then each wave emits its own
//     row: out[b,i,o] = sum_m rowR[m]*u[m] - rowI[m]*v[m] (and imag).
// This removes the k_output dispatch (+gap) and the 512 KB rowR/I round-trip;
// the output GEMM hides under other waves' streaming.
// ---------------------------------------------------------------------------
__global__ __launch_bounds__(256)
void k_stream_out(const float* __restrict__ Lr, const float* __restrict__ Li,
                  const float* __restrict__ sRi, const float* __restrict__ sIi,
                  const float* __restrict__ sRj, const float* __restrict__ sIj,
                  const float* __restrict__ cmax, const float* __restrict__ cinv,
                  const float* __restrict__ abr, const float* __restrict__ abi,
                  const float* __restrict__ par_, const float* __restrict__ pai_,
                  const float* __restrict__ Xr, const float* __restrict__ Xi,
                  const float* __restrict__ wr, const float* __restrict__ wi,
                  float* __restrict__ out) {
    __shared__ float luR[4][4][64];   // [m-plane][row-in-block][o]
    __shared__ float luI[4][4][64];
    const int lane = threadIdx.x & 63;
    const int wave = threadIdx.x >> 6;
    const int wid  = (blockIdx.x << 2) + wave;  // b*N + i (blocks never straddle b)
    const int b    = wid >> 10;
    const int i    = wid & 1023;
    const float br = abr[0], bi = abi[0], par = par_[0], pai = pai_[0];
    const float sri = sRi[wid], sii = sIi[wid];

    const float4* SRJ = (const float4*)(sRj + (b << 10));
    const float4* SIJ = (const float4*)(sIj + (b << 10));
    const float4* CMX = (const float4*)(cmax + (b << 10));
    const float4* CIV = (const float4*)(cinv + (b << 10));

    // Phase 1: 16 ar/ai pairs per lane, j = 4*(t*64+lane)+e.
    float arv[16], aiv[16];
#pragma unroll
    for (int t = 0; t < 4; ++t) {
        const int j4 = (t << 6) + lane;
        const float4 vr = SRJ[j4];
        const float4 vi = SIJ[j4];
        const float4 vm = CMX[j4];
        const float4 vs = CIV[j4];
        attn_coef(vr.x, vi.x, vm.x, vs.x, sri, sii, br, bi, par, pai,
                  arv[(t << 2) + 0], aiv[(t << 2) + 0]);
        attn_coef(vr.y, vi.y, vm.y, vs.y, sri, sii, br, bi, par, pai,
                  arv[(t << 2) + 1], aiv[(t << 2) + 1]);
        attn_coef(vr.z, vi.z, vm.z, vs.z, sri, sii, br, bi, par, pai,
                  arv[(t << 2) + 2], aiv[(t << 2) + 2]);
        attn_coef(vr.w, vi.w, vm.w, vs.w, sri, sii, br, bi, par, pai,
                  arv[(t << 2) + 3], aiv[(t << 2) + 3]);
    }

    // Phase 2: stream L[b,m,i,:], m=0..3; float4-index stride per m = 1<<18.
    const size_t base = ((size_t)b << 22) + ((size_t)i << 10);
    const nfloat4* LR = (const nfloat4*)(Lr + base);
    const nfloat4* LI = (const nfloat4*)(Li + base);

    float accR[4] = {0.f, 0.f, 0.f, 0.f};
    float accI[4] = {0.f, 0.f, 0.f, 0.f};
    nfloat4 rA[4], qA[4], rB[4], qB[4];
    LOAD_BURST(0, rA, qA);            // m0 -> A
    LOAD_BURST(1, rB, qB);            // m1 -> B  (2 bursts in flight)
    FMA_BURST(0, rA, qA);             // consume m0
    LOAD_BURST(2, rA, qA);            // m2 -> A  (keeps >=1 burst in flight)
    FMA_BURST(1, rB, qB);             // consume m1
    LOAD_BURST(3, rB, qB);            // m3 -> B
    FMA_BURST(2, rA, qA);             // consume m2
    FMA_BURST(3, rB, qB);             // consume m3

    // Butterfly: ALL lanes end up holding the full row sums rowR/rowI[m].
#pragma unroll
    for (int m = 0; m < 4; ++m) {
#pragma unroll
        for (int s = 32; s > 0; s >>= 1) {
            accR[m] += __shfl_xor(accR[m], s, 64);
            accI[m] += __shfl_xor(accI[m], s, 64);
        }
    }

    // Phase 3: output recombination, split by weight-plane m == wave.
    const int row0 = blockIdx.x << 2;
    float xrv[4], xiv[4];
#pragma unroll
    for (int r = 0; r < 4; ++r) {
        xrv[r] = Xr[(size_t)(row0 + r) * 64 + lane];
        xiv[r] = Xi[(size_t)(row0 + r) * 64 + lane];
    }
    float u[4] = {0.f, 0.f, 0.f, 0.f};
    float v[4] = {0.f, 0.f, 0.f, 0.f};
#pragma unroll 4
    for (int c = 0; c < 64; ++c) {
        const float wrv = wr[(((wave << 6) + c) << 6) + lane];
        const float wiv = wi[(((wave << 6) + c) << 6) + lane];
#pragma unroll
        for (int r = 0; r < 4; ++r) {
            u[r] += __shfl(xrv[r], c, 64) * wrv;
            v[r] += __shfl(xiv[r], c, 64) * wiv;
        }
    }
#pragma unroll
    for (int r = 0; r < 4; ++r) {
        luR[wave][r][lane] = u[r];
        luI[wave][r][lane] = v[r];
    }
    __syncthreads();
    float re = 0.f, im = 0.f;
#pragma unroll
    for (int m = 0; m < 4; ++m) {
        const float um = luR[m][wave][lane];
        const float vm = luI[m][wave][lane];
        re += accR[m] * um - accI[m] * vm;
        im += accI[m] * um + accR[m] * vm;
    }
    out[(size_t)wid * 64 + lane] = re;
    out[524288 + (size_t)wid * 64 + lane] = im;  // imag block
}

extern "C" void kernel_launch(void* const* d_in, const int* in_sizes, int n_in,
                              void* d_out, int out_size, void* d_ws, size_t ws_size,
                              hipStream_t stream) {
    const float* Xr  = (const float*)d_in[0];
    const float* Xi  = (const float*)d_in[1];
    const float* Lr  = (const float*)d_in[2];
    const float* Li  = (const float*)d_in[3];
    const float* wr  = (const float*)d_in[4];
    const float* wi  = (const float*)d_in[5];
    const float* awr = (const float*)d_in[6];
    const float* awi = (const float*)d_in[7];
    const float* abr = (const float*)d_in[8];
    const float* abi = (const float*)d_in[9];
    const float* par = (const float*)d_in[10];
    const float* pai = (const float*)d_in[11];
    float* out = (float*)d_out;

    // Workspace layout (floats):
    // sRi[8192] sIi[8192] sRj[8192] sIj[8192] cmax[8192] cinv[8192] = 192 KB
    float* ws   = (float*)d_ws;
    float* sRi  = ws;
    float* sIi  = ws + 8192;
    float* sRj  = ws + 16384;
    float* sIj  = ws + 24576;
    float* cmax = ws + 32768;
    float* cinv = ws + 40960;

    k_scores    <<<dim3(2048), dim3(256), 0, stream>>>(Xr, Xi, awr, awi, sRi, sIi, sRj, sIj);
    k_softmax   <<<dim3(2048), dim3(256), 0, stream>>>(sRi, sIi, sRj, sIj, cmax, cinv,
                                                       abr, abi, par, pai);
    k_stream_out<<<dim3(2048), dim3(256), 0, stream>>>(Lr, Li, sRi, sIi, sRj, sIj, cmax, cinv,
                                                       abr, abi, par, pai,
                                                       Xr, Xi, wr, wi, out);
}